// Round 2
// baseline (493.111 us; speedup 1.0000x reference)
//
#include <hip/hip_runtime.h>

// Problem constants
constexpr int Bb = 2;
constexpr int Ll = 2048;
constexpr int Dd = 2048;
constexpr int Hh = 16;
constexpr int Hd = 128;
constexpr int M  = Bb * Ll;   // 4096

typedef __attribute__((ext_vector_type(8)))  short s16x8;   // 8 bf16 (4 VGPRs)
typedef __attribute__((ext_vector_type(4)))  float f32x4;   // 16x16 C/D
typedef __attribute__((ext_vector_type(16))) float f32x16;  // 32x32 C/D

__device__ __forceinline__ unsigned short f2bf(float f) {
    union { float f; unsigned u; } v; v.f = f;
    unsigned r = v.u + 0x7fffu + ((v.u >> 16) & 1u);   // RNE
    return (unsigned short)(r >> 16);
}
__device__ __forceinline__ float bf2f(unsigned short b) {
    union { unsigned u; float f; } v; v.u = ((unsigned)b) << 16;
    return v.f;
}
__device__ __forceinline__ float fast_exp2(float x) {
#if __has_builtin(__builtin_amdgcn_exp2f)
    return __builtin_amdgcn_exp2f(x);
#else
    return exp2f(x);
#endif
}

// async global->LDS, 16 B per lane; lds dest = wave-uniform base + lane*16
__device__ __forceinline__ void gld16(const void* g, void* l) {
#if __has_builtin(__builtin_amdgcn_global_load_lds)
    __builtin_amdgcn_global_load_lds(
        (const __attribute__((address_space(1))) unsigned int*)g,
        (__attribute__((address_space(3))) unsigned int*)l, 16, 0, 0);
#else
    int lane = threadIdx.x & 63;
    ((int4*)l)[lane] = ((const int4*)g)[0];
#endif
}

// ---------------------------------------------------------------------------
// fp32 -> bf16 conversion (4 elems/thread)
// ---------------------------------------------------------------------------
__global__ __launch_bounds__(256)
void f2bf_kernel(const float* __restrict__ in, unsigned short* __restrict__ out, int n)
{
    int i = (blockIdx.x * 256 + threadIdx.x) * 4;
    if (i < n) {
        float4 v = *(const float4*)(in + i);
        ushort4 o;
        o.x = f2bf(v.x); o.y = f2bf(v.y); o.z = f2bf(v.z); o.w = f2bf(v.w);
        *(ushort4*)(out + i) = o;
    }
}

// ---------------------------------------------------------------------------
// Pipelined MFMA GEMM: C = A * W^T.  A [M][2048] bf16, W [N][2048] bf16.
// BM=256 x BN=128 tile, BK=64, 512 threads = 8 waves (4M x 2N), per-wave 64x64.
// 3 LDS slots (144 KiB), stage tile t+2 while computing tile t.
// Two phases per K-tile (ksub 0/1); counted vmcnt(6) once per K-tile (T3+T4).
// LDS reads XOR-swizzled (T2) with inverse swizzle pre-applied to the global
// source of global_load_lds (linear LDS dest; rule-21 both-sides discipline).
// MODE 0: qkv via blockIdx.z; q,k -> [b][h][l][d], v -> [b][h][d][l] (bf16)
// MODE 1: out-proj, fp32 store.
// ---------------------------------------------------------------------------
template<int MODE>
__global__ __launch_bounds__(512, 2)
void mfma_gemm(const unsigned short* __restrict__ A,
               const unsigned short* __restrict__ W0,
               const unsigned short* __restrict__ W1,
               const unsigned short* __restrict__ W2,
               unsigned short* __restrict__ O0,
               unsigned short* __restrict__ O1,
               unsigned short* __restrict__ O2,
               float* __restrict__ FO)
{
    constexpr int K  = 2048;
    constexpr int NT = K / 64;          // 32 K-tiles
    constexpr int SLOT_US = 24576;      // ushorts per slot: A 16384 + B 8192

    const unsigned short* W = W0;
    if (MODE == 0)
        W = (blockIdx.z == 0) ? W0 : (blockIdx.z == 1) ? W1 : W2;

    __shared__ unsigned short lds[3 * SLOT_US];   // 144 KiB

    const int t    = threadIdx.x;
    const int w    = t >> 6, lane = t & 63;
    const int wm   = w >> 1, wn = w & 1;
    const int m0   = blockIdx.y * 256, n0 = blockIdx.x * 128;
    const int r16  = lane & 15, q4 = lane >> 4;
    const int lxor = (r16 & 7) << 4;              // read-side swizzle XOR

    // staging lane constants: 8 lanes per 128B row; swizzled source column
    const int srow8 = lane >> 3;
    const int sgcol = (((lane & 7) ^ srow8) << 4);
    const char* Agb = (const char*)A;
    const char* Wgb = (const char*)W;

    f32x4 acc[4][4];
#pragma unroll
    for (int i = 0; i < 4; ++i)
#pragma unroll
        for (int j = 0; j < 4; ++j)
            acc[i][j] = (f32x4){0.f, 0.f, 0.f, 0.f};

    s16x8 af[4], bf[4];

// A stage: 32 instr/tile (ia = w*4+p), 8 rows x 128 B each, rows ia*8..+7
#define STAGE_A(tt, sl, p) do {                                              \
    int ia_ = w * 4 + (p);                                                   \
    gld16(Agb + (size_t)(m0 + ia_ * 8 + srow8) * (K * 2) + (tt) * 128 + sgcol, \
          &lds[(sl) * SLOT_US + ia_ * 512]); } while (0)
// B stage: 16 instr/tile (ib = w*2+p)
#define STAGE_B(tt, sl, p) do {                                              \
    int ib_ = w * 2 + (p);                                                   \
    gld16(Wgb + (size_t)(n0 + ib_ * 8 + srow8) * (K * 2) + (tt) * 128 + sgcol, \
          &lds[(sl) * SLOT_US + 16384 + ib_ * 512]); } while (0)

#define LOAD_FRAGS(sl, ksub) do {                                            \
    const char* Ab_ = (const char*)&lds[(sl) * SLOT_US];                     \
    const char* Bb_ = (const char*)&lds[(sl) * SLOT_US + 16384];             \
    int cc_ = ((ksub) * 64 + q4 * 16) ^ lxor;                                \
    _Pragma("unroll") for (int mi = 0; mi < 4; ++mi)                         \
        af[mi] = *(const s16x8*)(Ab_ + (wm * 64 + mi * 16 + r16) * 128 + cc_); \
    _Pragma("unroll") for (int ni = 0; ni < 4; ++ni)                         \
        bf[ni] = *(const s16x8*)(Bb_ + (wn * 64 + ni * 16 + r16) * 128 + cc_); \
} while (0)

#define DO_MFMA() do {                                                       \
    __builtin_amdgcn_s_setprio(1);                                           \
    _Pragma("unroll") for (int mi = 0; mi < 4; ++mi)                         \
    _Pragma("unroll") for (int ni = 0; ni < 4; ++ni)                         \
        acc[mi][ni] = __builtin_amdgcn_mfma_f32_16x16x32_bf16(                \
            af[mi], bf[ni], acc[mi][ni], 0, 0, 0);                           \
    __builtin_amdgcn_s_setprio(0);                                           \
} while (0)

    // prologue: stage tiles 0,1 into slots 0,1 (12 gld/wave), wait tile 0
    STAGE_A(0, 0, 0); STAGE_A(0, 0, 1); STAGE_B(0, 0, 0);
    STAGE_A(0, 0, 2); STAGE_A(0, 0, 3); STAGE_B(0, 0, 1);
    STAGE_A(1, 1, 0); STAGE_A(1, 1, 1); STAGE_B(1, 1, 0);
    STAGE_A(1, 1, 2); STAGE_A(1, 1, 3); STAGE_B(1, 1, 1);
    asm volatile("s_waitcnt vmcnt(6)" ::: "memory");
    __builtin_amdgcn_s_barrier();
    asm volatile("" ::: "memory");

    int slot = 0;
    for (int tt = 0; tt < NT; ++tt) {
        int snx = slot + 2; if (snx >= 3) snx -= 3;
        const bool pf = (tt + 2 < NT);

        // ---- phase 0 (ksub 0) ----
        LOAD_FRAGS(slot, 0);
        if (pf) { STAGE_A(tt + 2, snx, 0); STAGE_A(tt + 2, snx, 1); STAGE_B(tt + 2, snx, 0); }
        asm volatile("" ::: "memory");
        __builtin_amdgcn_s_barrier();
        asm volatile("s_waitcnt lgkmcnt(0)" ::: "memory");
        DO_MFMA();
        asm volatile("" ::: "memory");
        __builtin_amdgcn_s_barrier();
        asm volatile("" ::: "memory");

        // ---- phase 1 (ksub 1) ----
        LOAD_FRAGS(slot, 1);
        if (pf) { STAGE_A(tt + 2, snx, 2); STAGE_A(tt + 2, snx, 3); STAGE_B(tt + 2, snx, 1); }
        asm volatile("" ::: "memory");
        __builtin_amdgcn_s_barrier();
        asm volatile("s_waitcnt lgkmcnt(0)" ::: "memory");
        DO_MFMA();
        if (pf)               asm volatile("s_waitcnt vmcnt(6)" ::: "memory");
        else if (tt + 1 < NT) asm volatile("s_waitcnt vmcnt(0)" ::: "memory");
        asm volatile("" ::: "memory");
        __builtin_amdgcn_s_barrier();
        asm volatile("" ::: "memory");

        slot = (slot == 2) ? 0 : slot + 1;
    }

#undef STAGE_A
#undef STAGE_B
#undef LOAD_FRAGS
#undef DO_MFMA

    const int wrow = wm * 64, wcol = wn * 64;
    if (MODE == 0) {
        if (blockIdx.z < 2) {
            unsigned short* O = (blockIdx.z == 0) ? O0 : O1;
#pragma unroll
            for (int mi = 0; mi < 4; ++mi)
#pragma unroll
                for (int ni = 0; ni < 4; ++ni) {
                    int n = n0 + wcol + ni * 16 + r16;
                    int h = n >> 7, d = n & 127;
#pragma unroll
                    for (int r = 0; r < 4; ++r) {
                        int m = m0 + wrow + mi * 16 + q4 * 4 + r;
                        int b = m >> 11, l = m & 2047;
                        O[(((size_t)b * Hh + h) * Ll + l) * Hd + d] =
                            f2bf(acc[mi][ni][r]);
                    }
                }
        } else {
            // v: transposed store [b][h][d][l]; lane holds 4 consecutive l
#pragma unroll
            for (int mi = 0; mi < 4; ++mi) {
                int mb = m0 + wrow + mi * 16 + q4 * 4;
                int b = mb >> 11, l = mb & 2047;
#pragma unroll
                for (int ni = 0; ni < 4; ++ni) {
                    int n = n0 + wcol + ni * 16 + r16;
                    int h = n >> 7, d = n & 127;
                    ushort4 pk;
                    pk.x = f2bf(acc[mi][ni][0]);
                    pk.y = f2bf(acc[mi][ni][1]);
                    pk.z = f2bf(acc[mi][ni][2]);
                    pk.w = f2bf(acc[mi][ni][3]);
                    *(ushort4*)&O2[(((size_t)b * Hh + h) * Hd + d) * Ll + l] = pk;
                }
            }
        }
    } else {
#pragma unroll
        for (int mi = 0; mi < 4; ++mi)
#pragma unroll
            for (int ni = 0; ni < 4; ++ni) {
                int n = n0 + wcol + ni * 16 + r16;
#pragma unroll
                for (int r = 0; r < 4; ++r) {
                    int m = m0 + wrow + mi * 16 + q4 * 4 + r;
                    FO[(size_t)m * Dd + n] = acc[mi][ni][r];
                }
            }
    }
}

// ---------------------------------------------------------------------------
// RoPE in-place on bf16 q,k, vectorized short8 (G13).  16 threads/row,
// 16 rows/block; a row lives entirely in one wave, so the paired d / d^64
// reads complete (in wave program order) before the store — no barrier
// needed; compiler fence keeps the store after both loads.
// q additionally scaled by log2(e)/sqrt(128) (folds softmax scale + exp->exp2).
// grid: 8192 blocks (0..4095 = q, 4096..8191 = k).
// ---------------------------------------------------------------------------
__global__ __launch_bounds__(256)
void rope_bf16(unsigned short* __restrict__ q, unsigned short* __restrict__ k,
               const float* __restrict__ cosb, const float* __restrict__ sinb)
{
    const float QS = 0.1275175f;           // log2(e)/sqrt(128)
    const int t = threadIdx.x;
    int rblk = blockIdx.x;
    unsigned short* base;
    float sc;
    if (rblk < 4096) { base = q; sc = QS; }
    else             { base = k; sc = 1.0f; rblk -= 4096; }

    const int row = rblk * 16 + (t >> 4);  // [0, B*H*L)
    const int l   = row & (Ll - 1);
    const int d0  = (t & 15) * 8;
    unsigned short* xr = base + (size_t)row * Hd;

    s16x8 v0 = *(const s16x8*)(xr + d0);
    s16x8 vp = *(const s16x8*)(xr + (d0 ^ 64));
    const float* cp = cosb + (size_t)l * Hd + d0;
    const float* sp = sinb + (size_t)l * Hd + d0;
    float4 c0 = *(const float4*)cp,       c1 = *(const float4*)(cp + 4);
    float4 sa = *(const float4*)sp,       sb = *(const float4*)(sp + 4);
    const float cc[8] = {c0.x, c0.y, c0.z, c0.w, c1.x, c1.y, c1.z, c1.w};
    const float ss[8] = {sa.x, sa.y, sa.z, sa.w, sb.x, sb.y, sb.z, sb.w};
    const float sgn = (d0 < 64) ? -1.f : 1.f;

    s16x8 o;
#pragma unroll
    for (int j = 0; j < 8; ++j) {
        float a = bf2f((unsigned short)v0[j]);
        float p = bf2f((unsigned short)vp[j]);
        float res = fmaf(a, cc[j], sgn * p * ss[j]) * sc;
        o[j] = (short)f2bf(res);
    }
    asm volatile("" ::: "memory");         // loads (both halves) before store
    *(s16x8*)(xr + d0) = o;
}

// ---------------------------------------------------------------------------
// Flash attention, 32x32x16 bf16 MFMA, no-max softmax (exp2, scale pre-folded
// into q; scores are O(5), far from fp32 range limits; softmax is
// shift-invariant so skipping the running max is exact).
// Block = 128 q-rows of one (b,h); 4 waves; wave w owns rows w*32..+31.
// T14 async-STAGE: next K/V tile global->reg issued BEFORE this tile's
// compute (HBM latency hidden under QK^T+exp2+PV); reg->LDS write after the
// post-compute barrier (whose implicit vmcnt(0) drain is exactly the wait
// point).  T5 setprio around both MFMA clusters (blocks are barrier-
// independent across the CU, so waves sit at different phases).
// ---------------------------------------------------------------------------
__global__ __launch_bounds__(256)
void flash_attn(const unsigned short* __restrict__ q,
                const unsigned short* __restrict__ k,
                const unsigned short* __restrict__ vT,
                unsigned short* __restrict__ ctx)
{
    __shared__ unsigned short Ks[64 * 132];      // [key][d], stride 132 (2 banks)
    __shared__ unsigned short Vs[128 * 68];      // [d][key], stride 68
    __shared__ unsigned short Ps[4][32 * 68];    // per-wave [m][key]

    const int t = threadIdx.x;
    const int w = t >> 6, lane = t & 63;
    const int n32 = lane & 31, half = lane >> 5;
    const int bh = blockIdx.x >> 4;              // 16 q-tiles of 128 per (b,h)
    const int l0 = (blockIdx.x & 15) * 128;

    const unsigned short* qb = q  + ((size_t)bh * Ll + l0 + w * 32) * Hd;
    const unsigned short* kb = k  + (size_t)bh * Ll * Hd;
    const unsigned short* vb = vT + (size_t)bh * Hd * Ll;

    // staging lane coords
    const int krow = t >> 4;                     // 0..15 (+16/it)
    const int kcol = (t & 15) * 8;
    const int vrow = t >> 3;                     // 0..31 (+32/it)
    const int vcol = (t & 7) * 8;

    int4 krg[4], vrg[4];

#define ISSUE_KV(J0) do {                                                     \
    _Pragma("unroll") for (int it = 0; it < 4; ++it)                          \
        krg[it] = *(const int4*)(kb + (size_t)((J0) + it * 16 + krow) * Hd + kcol); \
    _Pragma("unroll") for (int it = 0; it < 4; ++it)                          \
        vrg[it] = *(const int4*)(vb + (size_t)(it * 32 + vrow) * Ll + (J0) + vcol); \
} while (0)

#define WRITE_KV() do {                                                       \
    _Pragma("unroll") for (int it = 0; it < 4; ++it)                          \
        *(int4*)&Ks[(it * 16 + krow) * 132 + kcol] = krg[it];                 \
    _Pragma("unroll") for (int it = 0; it < 4; ++it)                          \
        *(int4*)&Vs[(it * 32 + vrow) * 68 + vcol] = vrg[it];                  \
} while (0)

    // Q A-frags direct from global (A: m=lane&31, k=half*8+j per 16-k step)
    s16x8 qf[8];
#pragma unroll
    for (int ks = 0; ks < 8; ++ks)
        qf[ks] = *(const s16x8*)(qb + (size_t)n32 * Hd + ks * 16 + half * 8);

    f32x16 o[4];
    float lacc[16];
#pragma unroll
    for (int nt = 0; nt < 4; ++nt)
#pragma unroll
        for (int r = 0; r < 16; ++r) o[nt][r] = 0.f;
#pragma unroll
    for (int r = 0; r < 16; ++r) lacc[r] = 0.f;

    unsigned short* Pw = Ps[w];

    // prologue: stage tile 0
    ISSUE_KV(0);
    WRITE_KV();
    __syncthreads();

    for (int j0 = 0; j0 < Ll; j0 += 64) {
        const bool pf = (j0 + 64 < Ll);
        if (pf) ISSUE_KV(j0 + 64);             // in flight across the compute

        // S = Q K^T : two 32x32 C-tiles (keys j0.. and j0+32..)
        f32x16 s0, s1;
#pragma unroll
        for (int r = 0; r < 16; ++r) { s0[r] = 0.f; s1[r] = 0.f; }
        __builtin_amdgcn_s_setprio(1);
#pragma unroll
        for (int ks = 0; ks < 8; ++ks) {
            s16x8 b0 = *(const s16x8*)&Ks[n32 * 132 + ks * 16 + half * 8];
            s16x8 b1 = *(const s16x8*)&Ks[(32 + n32) * 132 + ks * 16 + half * 8];
            s0 = __builtin_amdgcn_mfma_f32_32x32x16_bf16(qf[ks], b0, s0, 0, 0, 0);
            s1 = __builtin_amdgcn_mfma_f32_32x32x16_bf16(qf[ks], b1, s1, 0, 0, 0);
        }
        __builtin_amdgcn_s_setprio(0);

        // P = exp2(S) (scale pre-folded into q); store bf16 to Ps; l += p
#pragma unroll
        for (int r = 0; r < 16; ++r) {
            int mrow = (r & 3) + 8 * (r >> 2) + 4 * half;
            float p0 = fast_exp2(s0[r]);
            float p1 = fast_exp2(s1[r]);
            lacc[r] += p0 + p1;
            union { float f; unsigned u; } u0, u1;
            u0.f = p0; u1.f = p1;
            Pw[mrow * 68 + n32]      = (unsigned short)((u0.u + 0x8000u) >> 16);
            Pw[mrow * 68 + 32 + n32] = (unsigned short)((u1.u + 0x8000u) >> 16);
        }

        // O += P V  (A = Ps[m][k], B = Vs[d][k]; wave-private, no barrier)
        __builtin_amdgcn_s_setprio(1);
#pragma unroll
        for (int kst = 0; kst < 4; ++kst) {
            s16x8 pf2 = *(const s16x8*)&Pw[n32 * 68 + kst * 16 + half * 8];
#pragma unroll
            for (int nt = 0; nt < 4; ++nt) {
                s16x8 vf = *(const s16x8*)&Vs[(nt * 32 + n32) * 68 + kst * 16 + half * 8];
                o[nt] = __builtin_amdgcn_mfma_f32_32x32x16_bf16(pf2, vf, o[nt], 0, 0, 0);
            }
        }
        __builtin_amdgcn_s_setprio(0);

        __syncthreads();                       // all reads of Ks/Vs done
        if (pf) WRITE_KV();                    // vmcnt(0) drained by barrier
        __syncthreads();                       // writes visible to all waves
    }

#undef ISSUE_KV
#undef WRITE_KV

    // epilogue: reduce l over the 32 key-lanes (bit5 preserved by masks<=16)
    float linv[16];
#pragma unroll
    for (int r = 0; r < 16; ++r) {
        float s = lacc[r];
        s += __shfl_xor(s, 1, 64);
        s += __shfl_xor(s, 2, 64);
        s += __shfl_xor(s, 4, 64);
        s += __shfl_xor(s, 8, 64);
        s += __shfl_xor(s, 16, 64);
        linv[r] = 1.0f / s;
    }

    const int b = bh >> 4, h = bh & 15;
#pragma unroll
    for (int nt = 0; nt < 4; ++nt)
#pragma unroll
        for (int r = 0; r < 16; ++r) {
            int mrow = (r & 3) + 8 * (r >> 2) + 4 * half;
            int lq = l0 + w * 32 + mrow;
            ctx[((size_t)(b * Ll + lq)) * Dd + h * Hd + nt * 32 + n32] =
                f2bf(o[nt][r] * linv[r]);
        }
}

// ---------------------------------------------------------------------------
// Workspace (96 MB): [Xb 16M][Wq 8M][Wk 8M][Wv 8M][Wo 8M][q 16M][k 16M][vT 16M]
// ctx reuses the Xb slot (X dead after QKV GEMM).
// ---------------------------------------------------------------------------
extern "C" void kernel_launch(void* const* d_in, const int* in_sizes, int n_in,
                              void* d_out, int out_size, void* d_ws, size_t ws_size,
                              hipStream_t stream)
{
    const float* hs   = (const float*)d_in[0];
    const float* cosb = (const float*)d_in[1];
    const float* sinb = (const float*)d_in[2];
    const float* wq   = (const float*)d_in[3];
    const float* wk   = (const float*)d_in[4];
    const float* wv   = (const float*)d_in[5];
    const float* wo   = (const float*)d_in[6];
    float* out = (float*)d_out;

    char* ws = (char*)d_ws;
    unsigned short* Xb  = (unsigned short*)(ws);
    unsigned short* Wqb = (unsigned short*)(ws + (16ull << 20));
    unsigned short* Wkb = (unsigned short*)(ws + (24ull << 20));
    unsigned short* Wvb = (unsigned short*)(ws + (32ull << 20));
    unsigned short* Wob = (unsigned short*)(ws + (40ull << 20));
    unsigned short* qb  = (unsigned short*)(ws + (48ull << 20));
    unsigned short* kb  = (unsigned short*)(ws + (64ull << 20));
    unsigned short* vTb = (unsigned short*)(ws + (80ull << 20));
    unsigned short* ctx = Xb;

    const int nX = M * Dd;          // 8388608
    const int nW = Dd * Dd;         // 4194304

    f2bf_kernel<<<dim3(nX / 4 / 256), dim3(256), 0, stream>>>(hs, Xb, nX);
    f2bf_kernel<<<dim3(nW / 4 / 256), dim3(256), 0, stream>>>(wq, Wqb, nW);
    f2bf_kernel<<<dim3(nW / 4 / 256), dim3(256), 0, stream>>>(wk, Wkb, nW);
    f2bf_kernel<<<dim3(nW / 4 / 256), dim3(256), 0, stream>>>(wv, Wvb, nW);
    f2bf_kernel<<<dim3(nW / 4 / 256), dim3(256), 0, stream>>>(wo, Wob, nW);

    // QKV projections (q,k -> [b][h][l][d]; v -> [b][h][d][l])
    // BM=256 x BN=128: grid 16x16x3 = 768 blocks = 3 full rounds of 256 CUs
    mfma_gemm<0><<<dim3(Dd / 128, M / 256, 3), dim3(512), 0, stream>>>(
        Xb, Wqb, Wkb, Wvb, qb, kb, vTb, nullptr);

    // RoPE: 16 rows/block, vectorized; blocks 0..4095 = q, 4096..8191 = k
    rope_bf16<<<dim3(2 * (Bb * Hh * Ll) / 16), dim3(256), 0, stream>>>(
        qb, kb, cosb, sinb);

    // Flash attention: 128 q-rows/block, 512 blocks (exactly 2/CU)
    flash_attn<<<dim3(Bb * Hh * (Ll / 128)), dim3(256), 0, stream>>>(qb, kb, vTb, ctx);

    // Output projection -> fp32 d_out (256 blocks = 1 full round)
    mfma_gemm<1><<<dim3(Dd / 128, M / 256, 1), dim3(512), 0, stream>>>(
        ctx, Wob, nullptr, nullptr, nullptr, nullptr, nullptr, out);
}

// Round 3
// 402.284 us; speedup vs baseline: 1.2258x; 1.2258x over previous
//
#include <hip/hip_runtime.h>

// Problem constants
constexpr int Bb = 2;
constexpr int Ll = 2048;
constexpr int Dd = 2048;
constexpr int Hh = 16;
constexpr int Hd = 128;
constexpr int M  = Bb * Ll;   // 4096

typedef __attribute__((ext_vector_type(8)))  short s16x8;   // 8 bf16 (4 VGPRs)
typedef __attribute__((ext_vector_type(4)))  float f32x4;   // 16x16 C/D
typedef __attribute__((ext_vector_type(16))) float f32x16;  // 32x32 C/D

__device__ __forceinline__ unsigned short f2bf(float f) {
    union { float f; unsigned u; } v; v.f = f;
    unsigned r = v.u + 0x7fffu + ((v.u >> 16) & 1u);   // RNE
    return (unsigned short)(r >> 16);
}
__device__ __forceinline__ float bf2f(unsigned short b) {
    union { unsigned u; float f; } v; v.u = ((unsigned)b) << 16;
    return v.f;
}
__device__ __forceinline__ float fast_exp2(float x) {
#if __has_builtin(__builtin_amdgcn_exp2f)
    return __builtin_amdgcn_exp2f(x);
#else
    return exp2f(x);
#endif
}

// async global->LDS, 16 B per lane; lds dest = wave-uniform base + lane*16
__device__ __forceinline__ void gld16(const void* g, void* l) {
#if __has_builtin(__builtin_amdgcn_global_load_lds)
    __builtin_amdgcn_global_load_lds(
        (const __attribute__((address_space(1))) unsigned int*)g,
        (__attribute__((address_space(3))) unsigned int*)l, 16, 0, 0);
#else
    int lane = threadIdx.x & 63;
    ((int4*)l)[lane] = ((const int4*)g)[0];
#endif
}

// ---------------------------------------------------------------------------
// fp32 -> bf16 conversion (4 elems/thread)
// ---------------------------------------------------------------------------
__global__ __launch_bounds__(256)
void f2bf_kernel(const float* __restrict__ in, unsigned short* __restrict__ out, int n)
{
    int i = (blockIdx.x * 256 + threadIdx.x) * 4;
    if (i < n) {
        float4 v = *(const float4*)(in + i);
        ushort4 o;
        o.x = f2bf(v.x); o.y = f2bf(v.y); o.z = f2bf(v.z); o.w = f2bf(v.w);
        *(ushort4*)(out + i) = o;
    }
}

// ---------------------------------------------------------------------------
// Pipelined MFMA GEMM: C = A * W^T.  A [M][2048] bf16, W [N][2048] bf16.
// BM=256 x BN=128 tile, BK=64, 512 threads = 8 waves (4M x 2N), per-wave 64x64.
// 3 LDS slots (144 KiB), stage tile t+2 while computing tile t.
// Two phases per K-tile (ksub 0/1); counted vmcnt(6) once per K-tile (T3+T4).
// LDS reads XOR-swizzled (T2) with inverse swizzle pre-applied to the global
// source of global_load_lds (linear LDS dest; rule-21 both-sides discipline).
// MODE 0: qkv via blockIdx.z; q,k -> [b][h][l][d], v -> [b][h][d][l] (bf16)
// MODE 1: out-proj, fp32 store.
// ---------------------------------------------------------------------------
template<int MODE>
__global__ __launch_bounds__(512, 2)
void mfma_gemm(const unsigned short* __restrict__ A,
               const unsigned short* __restrict__ W0,
               const unsigned short* __restrict__ W1,
               const unsigned short* __restrict__ W2,
               unsigned short* __restrict__ O0,
               unsigned short* __restrict__ O1,
               unsigned short* __restrict__ O2,
               float* __restrict__ FO)
{
    constexpr int K  = 2048;
    constexpr int NT = K / 64;          // 32 K-tiles
    constexpr int SLOT_US = 24576;      // ushorts per slot: A 16384 + B 8192

    const unsigned short* W = W0;
    if (MODE == 0)
        W = (blockIdx.z == 0) ? W0 : (blockIdx.z == 1) ? W1 : W2;

    __shared__ unsigned short lds[3 * SLOT_US];   // 144 KiB

    const int t    = threadIdx.x;
    const int w    = t >> 6, lane = t & 63;
    const int wm   = w >> 1, wn = w & 1;
    const int m0   = blockIdx.y * 256, n0 = blockIdx.x * 128;
    const int r16  = lane & 15, q4 = lane >> 4;
    const int lxor = (r16 & 7) << 4;              // read-side swizzle XOR

    // staging lane constants: 8 lanes per 128B row; swizzled source column
    const int srow8 = lane >> 3;
    const int sgcol = (((lane & 7) ^ srow8) << 4);
    const char* Agb = (const char*)A;
    const char* Wgb = (const char*)W;

    f32x4 acc[4][4];
#pragma unroll
    for (int i = 0; i < 4; ++i)
#pragma unroll
        for (int j = 0; j < 4; ++j)
            acc[i][j] = (f32x4){0.f, 0.f, 0.f, 0.f};

    s16x8 af[4], bf[4];

// A stage: 32 instr/tile (ia = w*4+p), 8 rows x 128 B each, rows ia*8..+7
#define STAGE_A(tt, sl, p) do {                                              \
    int ia_ = w * 4 + (p);                                                   \
    gld16(Agb + (size_t)(m0 + ia_ * 8 + srow8) * (K * 2) + (tt) * 128 + sgcol, \
          &lds[(sl) * SLOT_US + ia_ * 512]); } while (0)
// B stage: 16 instr/tile (ib = w*2+p)
#define STAGE_B(tt, sl, p) do {                                              \
    int ib_ = w * 2 + (p);                                                   \
    gld16(Wgb + (size_t)(n0 + ib_ * 8 + srow8) * (K * 2) + (tt) * 128 + sgcol, \
          &lds[(sl) * SLOT_US + 16384 + ib_ * 512]); } while (0)

#define LOAD_FRAGS(sl, ksub) do {                                            \
    const char* Ab_ = (const char*)&lds[(sl) * SLOT_US];                     \
    const char* Bb_ = (const char*)&lds[(sl) * SLOT_US + 16384];             \
    int cc_ = ((ksub) * 64 + q4 * 16) ^ lxor;                                \
    _Pragma("unroll") for (int mi = 0; mi < 4; ++mi)                         \
        af[mi] = *(const s16x8*)(Ab_ + (wm * 64 + mi * 16 + r16) * 128 + cc_); \
    _Pragma("unroll") for (int ni = 0; ni < 4; ++ni)                         \
        bf[ni] = *(const s16x8*)(Bb_ + (wn * 64 + ni * 16 + r16) * 128 + cc_); \
} while (0)

#define DO_MFMA() do {                                                       \
    __builtin_amdgcn_s_setprio(1);                                           \
    _Pragma("unroll") for (int mi = 0; mi < 4; ++mi)                         \
    _Pragma("unroll") for (int ni = 0; ni < 4; ++ni)                         \
        acc[mi][ni] = __builtin_amdgcn_mfma_f32_16x16x32_bf16(                \
            af[mi], bf[ni], acc[mi][ni], 0, 0, 0);                           \
    __builtin_amdgcn_s_setprio(0);                                           \
} while (0)

    // prologue: stage tiles 0,1 into slots 0,1 (12 gld/wave), wait tile 0
    STAGE_A(0, 0, 0); STAGE_A(0, 0, 1); STAGE_B(0, 0, 0);
    STAGE_A(0, 0, 2); STAGE_A(0, 0, 3); STAGE_B(0, 0, 1);
    STAGE_A(1, 1, 0); STAGE_A(1, 1, 1); STAGE_B(1, 1, 0);
    STAGE_A(1, 1, 2); STAGE_A(1, 1, 3); STAGE_B(1, 1, 1);
    asm volatile("s_waitcnt vmcnt(6)" ::: "memory");
    __builtin_amdgcn_s_barrier();
    asm volatile("" ::: "memory");

    int slot = 0;
    for (int tt = 0; tt < NT; ++tt) {
        int snx = slot + 2; if (snx >= 3) snx -= 3;
        const bool pf = (tt + 2 < NT);

        // ---- phase 0 (ksub 0) ----
        LOAD_FRAGS(slot, 0);
        if (pf) { STAGE_A(tt + 2, snx, 0); STAGE_A(tt + 2, snx, 1); STAGE_B(tt + 2, snx, 0); }
        asm volatile("" ::: "memory");
        __builtin_amdgcn_s_barrier();
        asm volatile("s_waitcnt lgkmcnt(0)" ::: "memory");
        DO_MFMA();
        asm volatile("" ::: "memory");
        __builtin_amdgcn_s_barrier();
        asm volatile("" ::: "memory");

        // ---- phase 1 (ksub 1) ----
        LOAD_FRAGS(slot, 1);
        if (pf) { STAGE_A(tt + 2, snx, 2); STAGE_A(tt + 2, snx, 3); STAGE_B(tt + 2, snx, 1); }
        asm volatile("" ::: "memory");
        __builtin_amdgcn_s_barrier();
        asm volatile("s_waitcnt lgkmcnt(0)" ::: "memory");
        DO_MFMA();
        if (pf)               asm volatile("s_waitcnt vmcnt(6)" ::: "memory");
        else if (tt + 1 < NT) asm volatile("s_waitcnt vmcnt(0)" ::: "memory");
        asm volatile("" ::: "memory");
        __builtin_amdgcn_s_barrier();
        asm volatile("" ::: "memory");

        slot = (slot == 2) ? 0 : slot + 1;
    }

#undef STAGE_A
#undef STAGE_B
#undef LOAD_FRAGS
#undef DO_MFMA

    const int wrow = wm * 64, wcol = wn * 64;
    if (MODE == 0) {
        if (blockIdx.z < 2) {
            unsigned short* O = (blockIdx.z == 0) ? O0 : O1;
#pragma unroll
            for (int mi = 0; mi < 4; ++mi)
#pragma unroll
                for (int ni = 0; ni < 4; ++ni) {
                    int n = n0 + wcol + ni * 16 + r16;
                    int h = n >> 7, d = n & 127;
#pragma unroll
                    for (int r = 0; r < 4; ++r) {
                        int m = m0 + wrow + mi * 16 + q4 * 4 + r;
                        int b = m >> 11, l = m & 2047;
                        O[(((size_t)b * Hh + h) * Ll + l) * Hd + d] =
                            f2bf(acc[mi][ni][r]);
                    }
                }
        } else {
            // v: transposed store [b][h][d][l]; lane holds 4 consecutive l
#pragma unroll
            for (int mi = 0; mi < 4; ++mi) {
                int mb = m0 + wrow + mi * 16 + q4 * 4;
                int b = mb >> 11, l = mb & 2047;
#pragma unroll
                for (int ni = 0; ni < 4; ++ni) {
                    int n = n0 + wcol + ni * 16 + r16;
                    int h = n >> 7, d = n & 127;
                    ushort4 pk;
                    pk.x = f2bf(acc[mi][ni][0]);
                    pk.y = f2bf(acc[mi][ni][1]);
                    pk.z = f2bf(acc[mi][ni][2]);
                    pk.w = f2bf(acc[mi][ni][3]);
                    *(ushort4*)&O2[(((size_t)b * Hh + h) * Hd + d) * Ll + l] = pk;
                }
            }
        }
    } else {
#pragma unroll
        for (int mi = 0; mi < 4; ++mi)
#pragma unroll
            for (int ni = 0; ni < 4; ++ni) {
                int n = n0 + wcol + ni * 16 + r16;
#pragma unroll
                for (int r = 0; r < 4; ++r) {
                    int m = m0 + wrow + mi * 16 + q4 * 4 + r;
                    FO[(size_t)m * Dd + n] = acc[mi][ni][r];
                }
            }
    }
}

// ---------------------------------------------------------------------------
// RoPE in-place on bf16 q,k, vectorized short8 (G13).  16 threads/row,
// 16 rows/block; a row lives entirely in one wave, so the paired d / d^64
// reads complete (in wave program order) before the store — no barrier
// needed; compiler fence keeps the store after both loads.
// q additionally scaled by log2(e)/sqrt(128) (folds softmax scale + exp->exp2).
// grid: 8192 blocks (0..4095 = q, 4096..8191 = k).
// ---------------------------------------------------------------------------
__global__ __launch_bounds__(256)
void rope_bf16(unsigned short* __restrict__ q, unsigned short* __restrict__ k,
               const float* __restrict__ cosb, const float* __restrict__ sinb)
{
    const float QS = 0.1275175f;           // log2(e)/sqrt(128)
    const int t = threadIdx.x;
    int rblk = blockIdx.x;
    unsigned short* base;
    float sc;
    if (rblk < 4096) { base = q; sc = QS; }
    else             { base = k; sc = 1.0f; rblk -= 4096; }

    const int row = rblk * 16 + (t >> 4);  // [0, B*H*L)
    const int l   = row & (Ll - 1);
    const int d0  = (t & 15) * 8;
    unsigned short* xr = base + (size_t)row * Hd;

    s16x8 v0 = *(const s16x8*)(xr + d0);
    s16x8 vp = *(const s16x8*)(xr + (d0 ^ 64));
    const float* cp = cosb + (size_t)l * Hd + d0;
    const float* sp = sinb + (size_t)l * Hd + d0;
    float4 c0 = *(const float4*)cp,       c1 = *(const float4*)(cp + 4);
    float4 sa = *(const float4*)sp,       sb = *(const float4*)(sp + 4);
    const float cc[8] = {c0.x, c0.y, c0.z, c0.w, c1.x, c1.y, c1.z, c1.w};
    const float ss[8] = {sa.x, sa.y, sa.z, sa.w, sb.x, sb.y, sb.z, sb.w};
    const float sgn = (d0 < 64) ? -1.f : 1.f;

    s16x8 o;
#pragma unroll
    for (int j = 0; j < 8; ++j) {
        float a = bf2f((unsigned short)v0[j]);
        float p = bf2f((unsigned short)vp[j]);
        float res = fmaf(a, cc[j], sgn * p * ss[j]) * sc;
        o[j] = (short)f2bf(res);
    }
    asm volatile("" ::: "memory");         // loads (both halves) before store
    *(s16x8*)(xr + d0) = o;
}

// ---------------------------------------------------------------------------
// Flash attention, 32x32x16 bf16 MFMA, no-max softmax (exp2, scale pre-folded
// into q; scores are O(5), far from fp32 range limits; softmax is
// shift-invariant so skipping the running max is exact).
// Block = 128 q-rows of one (b,h); 4 waves; wave w owns rows w*32..+31.
// Double-buffered async staging via global_load_lds (no VGPR round trip ->
// no spill, unlike reg-staging): tile t+1's 8 gld_lds issued BEFORE tile t's
// compute; __syncthreads() at tile end (implicit vmcnt(0)+lgkmcnt(0) drain)
// is the wait point -> HBM/L2 latency hidden under 48 MFMA + 32 exp2.
// One barrier per tile.  Linear LDS tiles (gld_lds constraint) with
// byte^=((row&7)<<4) XOR swizzle on reads and the inverse pre-applied to the
// per-lane GLOBAL source (rule-21 both-sides).  Ps stride 64 + same swizzle.
// LDS = 2*16K (K) + 2*16K (V) + 16K (P) = 80 KiB -> exactly 2 blocks/CU.
// ---------------------------------------------------------------------------
__global__ __launch_bounds__(256)
void flash_attn(const unsigned short* __restrict__ q,
                const unsigned short* __restrict__ k,
                const unsigned short* __restrict__ vT,
                unsigned short* __restrict__ ctx)
{
    __shared__ unsigned short Ks[2][64 * 128];   // [key][d] linear
    __shared__ unsigned short Vs[2][128 * 64];   // [d][key] linear
    __shared__ unsigned short Ps[4][32 * 64];    // per-wave [m][key]

    const int t = threadIdx.x;
    const int w = t >> 6, lane = t & 63;
    const int n32 = lane & 31, half = lane >> 5;
    const int bh = blockIdx.x >> 4;              // 16 q-tiles of 128 per (b,h)
    const int l0 = (blockIdx.x & 15) * 128;

    const unsigned short* qb = q  + ((size_t)bh * Ll + l0 + w * 32) * Hd;
    const unsigned short* kb = k  + (size_t)bh * Ll * Hd;
    const unsigned short* vb = vT + (size_t)bh * Hd * Ll;

    // staging lane coords (per gld16: 64 lanes x 16 B = 1 KiB)
    const int k_r = lane >> 4, k_u = lane & 15;  // K: 4 rows x 256 B per instr
    const int v_r = lane >> 3, v_u = lane & 7;   // V: 8 rows x 128 B per instr

    // stage one 64-key tile: K 16 instr + V 16 instr, 8 per wave.
    // global source column pre-swizzled by ^(row&7) in 16 B units.
#define STAGE(J0, bsel) do {                                                  \
    _Pragma("unroll") for (int p = 0; p < 4; ++p) {                           \
        int j_ = w * 4 + p;                                                   \
        int row_ = j_ * 4 + k_r;                                              \
        gld16(kb + (size_t)((J0) + row_) * Hd + ((k_u ^ (row_ & 7)) * 8),     \
              &Ks[bsel][j_ * 512]);                                           \
    }                                                                         \
    _Pragma("unroll") for (int p = 0; p < 4; ++p) {                           \
        int j_ = w * 4 + p;                                                   \
        int row_ = j_ * 8 + v_r;                                              \
        gld16(vb + (size_t)row_ * Ll + (J0) + ((v_u ^ (row_ & 7)) * 8),       \
              &Vs[bsel][j_ * 512]);                                           \
    }                                                                         \
} while (0)

    // Q A-frags direct from global (A: m=lane&31, k=half*8+j per 16-k step)
    s16x8 qf[8];
#pragma unroll
    for (int ks = 0; ks < 8; ++ks)
        qf[ks] = *(const s16x8*)(qb + (size_t)n32 * Hd + ks * 16 + half * 8);

    f32x16 o[4];
    float lacc[16];
#pragma unroll
    for (int nt = 0; nt < 4; ++nt)
#pragma unroll
        for (int r = 0; r < 16; ++r) o[nt][r] = 0.f;
#pragma unroll
    for (int r = 0; r < 16; ++r) lacc[r] = 0.f;

    unsigned short* Pw = Ps[w];
    const int psw = (n32 & 7) << 3;              // read-side swizzle (row n32)

    // prologue: stage tile 0 into buf 0
    STAGE(0, 0);
    __syncthreads();

    int buf = 0;
    for (int j0 = 0; j0 < Ll; j0 += 64) {
        if (j0 + 64 < Ll) STAGE(j0 + 64, buf ^ 1);   // in flight across compute

        // S = Q K^T : two 32x32 C-tiles (keys j0.. and j0+32..)
        f32x16 s0, s1;
#pragma unroll
        for (int r = 0; r < 16; ++r) { s0[r] = 0.f; s1[r] = 0.f; }
        __builtin_amdgcn_s_setprio(1);
#pragma unroll
        for (int ks = 0; ks < 8; ++ks) {
            int kc = (ks * 16 + half * 8) ^ psw;
            s16x8 b0 = *(const s16x8*)&Ks[buf][n32 * 128 + kc];
            s16x8 b1 = *(const s16x8*)&Ks[buf][(32 + n32) * 128 + kc];
            s0 = __builtin_amdgcn_mfma_f32_32x32x16_bf16(qf[ks], b0, s0, 0, 0, 0);
            s1 = __builtin_amdgcn_mfma_f32_32x32x16_bf16(qf[ks], b1, s1, 0, 0, 0);
        }
        __builtin_amdgcn_s_setprio(0);

        // P = exp2(S) (scale pre-folded into q); store bf16 to Ps; l += p
#pragma unroll
        for (int r = 0; r < 16; ++r) {
            int mrow = (r & 3) + 8 * (r >> 2) + 4 * half;
            int sw = (mrow & 7) << 3;
            float p0 = fast_exp2(s0[r]);
            float p1 = fast_exp2(s1[r]);
            lacc[r] += p0 + p1;
            union { float f; unsigned u; } u0, u1;
            u0.f = p0; u1.f = p1;
            Pw[mrow * 64 + (n32 ^ sw)]        = (unsigned short)((u0.u + 0x8000u) >> 16);
            Pw[mrow * 64 + ((32 + n32) ^ sw)] = (unsigned short)((u1.u + 0x8000u) >> 16);
        }

        // O += P V  (A = Ps[m][k], B = Vs[d][k]; wave-private, no barrier)
        __builtin_amdgcn_s_setprio(1);
#pragma unroll
        for (int kst = 0; kst < 4; ++kst) {
            int cc = (kst * 16 + half * 8) ^ psw;
            s16x8 pf2 = *(const s16x8*)&Pw[n32 * 64 + cc];
#pragma unroll
            for (int nt = 0; nt < 4; ++nt) {
                s16x8 vf = *(const s16x8*)&Vs[buf][(nt * 32 + n32) * 64 + cc];
                o[nt] = __builtin_amdgcn_mfma_f32_32x32x16_bf16(pf2, vf, o[nt], 0, 0, 0);
            }
        }
        __builtin_amdgcn_s_setprio(0);

        __syncthreads();     // drains vmcnt(0): next tile staged; buffer swap
        buf ^= 1;
    }

#undef STAGE

    // epilogue: reduce l over the 32 key-lanes (bit5 preserved by masks<=16)
    float linv[16];
#pragma unroll
    for (int r = 0; r < 16; ++r) {
        float s = lacc[r];
        s += __shfl_xor(s, 1, 64);
        s += __shfl_xor(s, 2, 64);
        s += __shfl_xor(s, 4, 64);
        s += __shfl_xor(s, 8, 64);
        s += __shfl_xor(s, 16, 64);
        linv[r] = 1.0f / s;
    }

    const int b = bh >> 4, h = bh & 15;
#pragma unroll
    for (int nt = 0; nt < 4; ++nt)
#pragma unroll
        for (int r = 0; r < 16; ++r) {
            int mrow = (r & 3) + 8 * (r >> 2) + 4 * half;
            int lq = l0 + w * 32 + mrow;
            ctx[((size_t)(b * Ll + lq)) * Dd + h * Hd + nt * 32 + n32] =
                f2bf(o[nt][r] * linv[r]);
        }
}

// ---------------------------------------------------------------------------
// Workspace (96 MB): [Xb 16M][Wq 8M][Wk 8M][Wv 8M][Wo 8M][q 16M][k 16M][vT 16M]
// ctx reuses the Xb slot (X dead after QKV GEMM).
// ---------------------------------------------------------------------------
extern "C" void kernel_launch(void* const* d_in, const int* in_sizes, int n_in,
                              void* d_out, int out_size, void* d_ws, size_t ws_size,
                              hipStream_t stream)
{
    const float* hs   = (const float*)d_in[0];
    const float* cosb = (const float*)d_in[1];
    const float* sinb = (const float*)d_in[2];
    const float* wq   = (const float*)d_in[3];
    const float* wk   = (const float*)d_in[4];
    const float* wv   = (const float*)d_in[5];
    const float* wo   = (const float*)d_in[6];
    float* out = (float*)d_out;

    char* ws = (char*)d_ws;
    unsigned short* Xb  = (unsigned short*)(ws);
    unsigned short* Wqb = (unsigned short*)(ws + (16ull << 20));
    unsigned short* Wkb = (unsigned short*)(ws + (24ull << 20));
    unsigned short* Wvb = (unsigned short*)(ws + (32ull << 20));
    unsigned short* Wob = (unsigned short*)(ws + (40ull << 20));
    unsigned short* qb  = (unsigned short*)(ws + (48ull << 20));
    unsigned short* kb  = (unsigned short*)(ws + (64ull << 20));
    unsigned short* vTb = (unsigned short*)(ws + (80ull << 20));
    unsigned short* ctx = Xb;

    const int nX = M * Dd;          // 8388608
    const int nW = Dd * Dd;         // 4194304

    f2bf_kernel<<<dim3(nX / 4 / 256), dim3(256), 0, stream>>>(hs, Xb, nX);
    f2bf_kernel<<<dim3(nW / 4 / 256), dim3(256), 0, stream>>>(wq, Wqb, nW);
    f2bf_kernel<<<dim3(nW / 4 / 256), dim3(256), 0, stream>>>(wk, Wkb, nW);
    f2bf_kernel<<<dim3(nW / 4 / 256), dim3(256), 0, stream>>>(wv, Wvb, nW);
    f2bf_kernel<<<dim3(nW / 4 / 256), dim3(256), 0, stream>>>(wo, Wob, nW);

    // QKV projections (q,k -> [b][h][l][d]; v -> [b][h][d][l])
    // BM=256 x BN=128: grid 16x16x3 = 768 blocks = 3 full rounds of 256 CUs
    mfma_gemm<0><<<dim3(Dd / 128, M / 256, 3), dim3(512), 0, stream>>>(
        Xb, Wqb, Wkb, Wvb, qb, kb, vTb, nullptr);

    // RoPE: 16 rows/block, vectorized; blocks 0..4095 = q, 4096..8191 = k
    rope_bf16<<<dim3(2 * (Bb * Hh * Ll) / 16), dim3(256), 0, stream>>>(
        qb, kb, cosb, sinb);

    // Flash attention: 128 q-rows/block, 512 blocks (exactly 2/CU)
    flash_attn<<<dim3(Bb * Hh * (Ll / 128)), dim3(256), 0, stream>>>(qb, kb, vTb, ctx);

    // Output projection -> fp32 d_out (256 blocks = 1 full round)
    mfma_gemm<1><<<dim3(Dd / 128, M / 256, 1), dim3(512), 0, stream>>>(
        ctx, Wob, nullptr, nullptr, nullptr, nullptr, nullptr, out);
}

// Round 4
// 391.924 us; speedup vs baseline: 1.2582x; 1.0264x over previous
//
#include <hip/hip_runtime.h>

// Problem constants
constexpr int Bb = 2;
constexpr int Ll = 2048;
constexpr int Dd = 2048;
constexpr int Hh = 16;
constexpr int Hd = 128;
constexpr int M  = Bb * Ll;   // 4096

typedef __attribute__((ext_vector_type(8)))  short s16x8;   // 8 bf16 (4 VGPRs)
typedef __attribute__((ext_vector_type(4)))  float f32x4;   // 16x16 C/D
typedef __attribute__((ext_vector_type(16))) float f32x16;  // 32x32 C/D

__device__ __forceinline__ unsigned short f2bf(float f) {
    union { float f; unsigned u; } v; v.f = f;
    unsigned r = v.u + 0x7fffu + ((v.u >> 16) & 1u);   // RNE
    return (unsigned short)(r >> 16);
}
__device__ __forceinline__ float bf2f(unsigned short b) {
    union { unsigned u; float f; } v; v.u = ((unsigned)b) << 16;
    return v.f;
}
__device__ __forceinline__ float fast_exp2(float x) {
#if __has_builtin(__builtin_amdgcn_exp2f)
    return __builtin_amdgcn_exp2f(x);
#else
    return exp2f(x);
#endif
}

// async global->LDS, 16 B per lane; lds dest = wave-uniform base + lane*16
__device__ __forceinline__ void gld16(const void* g, void* l) {
#if __has_builtin(__builtin_amdgcn_global_load_lds)
    __builtin_amdgcn_global_load_lds(
        (const __attribute__((address_space(1))) unsigned int*)g,
        (__attribute__((address_space(3))) unsigned int*)l, 16, 0, 0);
#else
    int lane = threadIdx.x & 63;
    ((int4*)l)[lane] = ((const int4*)g)[0];
#endif
}

// ---------------------------------------------------------------------------
// fp32 -> bf16 conversion (4 elems/thread)
// ---------------------------------------------------------------------------
__global__ __launch_bounds__(256)
void f2bf_kernel(const float* __restrict__ in, unsigned short* __restrict__ out, int n)
{
    int i = (blockIdx.x * 256 + threadIdx.x) * 4;
    if (i < n) {
        float4 v = *(const float4*)(in + i);
        ushort4 o;
        o.x = f2bf(v.x); o.y = f2bf(v.y); o.z = f2bf(v.z); o.w = f2bf(v.w);
        *(ushort4*)(out + i) = o;
    }
}

// ---------------------------------------------------------------------------
// Fused QKV GEMM: C = A * Wall^T.  A [4096][2048] bf16, Wall [6144][2048]
// (= wq;wk;wv stacked contiguously in workspace).
// BM=256 x BN=192 tile, BK=64, 512 threads = 8 waves (2M x 4N),
// per-wave 128x48 (acc 8x3 f32x4 = 96 VGPR) -> 0.458 ds_reads/MFMA.
// ONE barrier per K-tile: within a tile all waves only READ the slot
// (written the previous tile), so no intra-tile hazard; plain-C ds_reads
// let the compiler emit fine-grained lgkmcnt so ks1 frag reads overlap
// ks0 MFMAs (de-serializes LDS-read time vs MFMA time).
// 2-slot double buffer (112 KiB); stage tile t+1 during compute of t into
// slot^1 (readers of slot^1 = tile t-1, retired before t-1's barrier);
// vmcnt(0) + barrier at tile end.
// LDS reads XOR-swizzled (T2), inverse pre-applied to gld_lds global source.
// Grid 32x16 = 512 blocks = exactly 2 full rounds of 256 CUs.
// Epilogue routes per frag-column (16-aligned, never straddles q/k/v):
// q,k -> [b][h][l][d]; v -> [b][h][d][l] transposed.
// ---------------------------------------------------------------------------
__global__ __launch_bounds__(512, 2)
void mfma_gemm_qkv(const unsigned short* __restrict__ A,
                   const unsigned short* __restrict__ Wall,
                   unsigned short* __restrict__ Oq,
                   unsigned short* __restrict__ Ok,
                   unsigned short* __restrict__ Ov)
{
    constexpr int K  = 2048;
    constexpr int NT = K / 64;              // 32 K-tiles
    constexpr int BM = 256, BN = 192;
    constexpr int SLOT_US = (BM + BN) * 64; // 28672 ushorts = 56 KiB

    __shared__ unsigned short lds[2 * SLOT_US];   // 112 KiB

    const int t    = threadIdx.x;
    const int w    = t >> 6, lane = t & 63;
    const int wm   = w >> 2, wn = w & 3;          // 2M x 4N
    const int m0   = blockIdx.y * BM, n0 = blockIdx.x * BN;
    const int r16  = lane & 15, q4 = lane >> 4;
    const int lxor = (r16 & 7) << 4;              // read-side swizzle XOR

    // staging lane constants: 8 lanes per 128B row; swizzled source column
    const int srow8 = lane >> 3;
    const int sgcol = (((lane & 7) ^ srow8) << 4);
    const char* Agb = (const char*)A;
    const char* Wgb = (const char*)Wall;

    f32x4 acc[8][3];
#pragma unroll
    for (int i = 0; i < 8; ++i)
#pragma unroll
        for (int j = 0; j < 3; ++j)
            acc[i][j] = (f32x4){0.f, 0.f, 0.f, 0.f};

// stage one K-tile: A 32 gld (ia=w*4+p), B 24 gld (ib=w*3+p); 7 per wave
#define STAGE(tt, sl) do {                                                   \
    _Pragma("unroll") for (int p = 0; p < 4; ++p) {                          \
        int ia_ = w * 4 + p;                                                 \
        gld16(Agb + (size_t)(m0 + ia_ * 8 + srow8) * (K * 2) + (tt) * 128 + sgcol, \
              &lds[(sl) * SLOT_US + ia_ * 512]);                             \
    }                                                                        \
    _Pragma("unroll") for (int p = 0; p < 3; ++p) {                          \
        int ib_ = w * 3 + p;                                                 \
        gld16(Wgb + (size_t)(n0 + ib_ * 8 + srow8) * (K * 2) + (tt) * 128 + sgcol, \
              &lds[(sl) * SLOT_US + BM * 64 + ib_ * 512]);                   \
    }                                                                        \
} while (0)

    // prologue: stage tile 0 into slot 0
    STAGE(0, 0);
    asm volatile("s_waitcnt vmcnt(0)" ::: "memory");
    __builtin_amdgcn_s_barrier();
    asm volatile("" ::: "memory");

    int slot = 0;
    for (int tt = 0; tt < NT; ++tt) {
        const char* Ab = (const char*)&lds[slot * SLOT_US];
        const char* Bp = (const char*)&lds[slot * SLOT_US + BM * 64];
        const int c0 = (q4 * 16) ^ lxor;         // ks=0 byte col (swizzled)
        const int c1 = (64 + q4 * 16) ^ lxor;    // ks=1

        s16x8 a0[8], a1[8], b0[3], b1[3];
#pragma unroll
        for (int mi = 0; mi < 8; ++mi) {
            int rb = (wm * 128 + mi * 16 + r16) * 128;
            a0[mi] = *(const s16x8*)(Ab + rb + c0);
        }
#pragma unroll
        for (int ni = 0; ni < 3; ++ni) {
            int rb = (wn * 48 + ni * 16 + r16) * 128;
            b0[ni] = *(const s16x8*)(Bp + rb + c0);
        }
        if (tt + 1 < NT) STAGE(tt + 1, slot ^ 1);
#pragma unroll
        for (int mi = 0; mi < 8; ++mi) {
            int rb = (wm * 128 + mi * 16 + r16) * 128;
            a1[mi] = *(const s16x8*)(Ab + rb + c1);
        }
#pragma unroll
        for (int ni = 0; ni < 3; ++ni) {
            int rb = (wn * 48 + ni * 16 + r16) * 128;
            b1[ni] = *(const s16x8*)(Bp + rb + c1);
        }

        __builtin_amdgcn_s_setprio(1);
#pragma unroll
        for (int mi = 0; mi < 8; ++mi)
#pragma unroll
            for (int ni = 0; ni < 3; ++ni)
                acc[mi][ni] = __builtin_amdgcn_mfma_f32_16x16x32_bf16(
                    a0[mi], b0[ni], acc[mi][ni], 0, 0, 0);
#pragma unroll
        for (int mi = 0; mi < 8; ++mi)
#pragma unroll
            for (int ni = 0; ni < 3; ++ni)
                acc[mi][ni] = __builtin_amdgcn_mfma_f32_16x16x32_bf16(
                    a1[mi], b1[ni], acc[mi][ni], 0, 0, 0);
        __builtin_amdgcn_s_setprio(0);

        asm volatile("s_waitcnt vmcnt(0)" ::: "memory");  // t+1 staged
        __builtin_amdgcn_s_barrier();
        asm volatile("" ::: "memory");
        slot ^= 1;
    }
#undef STAGE

    // epilogue: per frag-column routing (nb 16-aligned -> wave-uniform nsel)
#pragma unroll
    for (int ni = 0; ni < 3; ++ni) {
        int nb   = n0 + wn * 48 + ni * 16;
        int nsel = nb >> 11;                // 0=q, 1=k, 2=v
        int nr   = nb & 2047;
        int h    = nr >> 7;
        int d    = (nr & 127) + r16;
        if (nsel < 2) {
            unsigned short* O = nsel ? Ok : Oq;
#pragma unroll
            for (int mi = 0; mi < 8; ++mi)
#pragma unroll
                for (int r = 0; r < 4; ++r) {
                    int m = m0 + wm * 128 + mi * 16 + q4 * 4 + r;
                    int b = m >> 11, l = m & 2047;
                    O[(((size_t)b * Hh + h) * Ll + l) * Hd + d] =
                        f2bf(acc[mi][ni][r]);
                }
        } else {
            // v: transposed store [b][h][d][l]; lane holds 4 consecutive l
#pragma unroll
            for (int mi = 0; mi < 8; ++mi) {
                int mb = m0 + wm * 128 + mi * 16 + q4 * 4;
                int b = mb >> 11, l = mb & 2047;
                ushort4 pk;
                pk.x = f2bf(acc[mi][ni][0]);
                pk.y = f2bf(acc[mi][ni][1]);
                pk.z = f2bf(acc[mi][ni][2]);
                pk.w = f2bf(acc[mi][ni][3]);
                *(ushort4*)&Ov[(((size_t)b * Hh + h) * Hd + d) * Ll + l] = pk;
            }
        }
    }
}

// ---------------------------------------------------------------------------
// Out-projection GEMM (proven r3 structure): C = A * W^T, fp32 store.
// BM=256 x BN=128, BK=64, 8 waves (4M x 2N), per-wave 64x64, 3 LDS slots,
// counted vmcnt(6), XOR swizzle.  Grid 16x16 = 256 blocks = 1 full round.
// ---------------------------------------------------------------------------
__global__ __launch_bounds__(512, 2)
void mfma_gemm_out(const unsigned short* __restrict__ A,
                   const unsigned short* __restrict__ W,
                   float* __restrict__ FO)
{
    constexpr int K  = 2048;
    constexpr int NT = K / 64;          // 32 K-tiles
    constexpr int SLOT_US = 24576;      // A 16384 + B 8192

    __shared__ unsigned short lds[3 * SLOT_US];   // 144 KiB

    const int t    = threadIdx.x;
    const int w    = t >> 6, lane = t & 63;
    const int wm   = w >> 1, wn = w & 1;
    const int m0   = blockIdx.y * 256, n0 = blockIdx.x * 128;
    const int r16  = lane & 15, q4 = lane >> 4;
    const int lxor = (r16 & 7) << 4;

    const int srow8 = lane >> 3;
    const int sgcol = (((lane & 7) ^ srow8) << 4);
    const char* Agb = (const char*)A;
    const char* Wgb = (const char*)W;

    f32x4 acc[4][4];
#pragma unroll
    for (int i = 0; i < 4; ++i)
#pragma unroll
        for (int j = 0; j < 4; ++j)
            acc[i][j] = (f32x4){0.f, 0.f, 0.f, 0.f};

    s16x8 af[4], bf[4];

#define STAGE_A(tt, sl, p) do {                                              \
    int ia_ = w * 4 + (p);                                                   \
    gld16(Agb + (size_t)(m0 + ia_ * 8 + srow8) * (K * 2) + (tt) * 128 + sgcol, \
          &lds[(sl) * SLOT_US + ia_ * 512]); } while (0)
#define STAGE_B(tt, sl, p) do {                                              \
    int ib_ = w * 2 + (p);                                                   \
    gld16(Wgb + (size_t)(n0 + ib_ * 8 + srow8) * (K * 2) + (tt) * 128 + sgcol, \
          &lds[(sl) * SLOT_US + 16384 + ib_ * 512]); } while (0)

#define LOAD_FRAGS(sl, ksub) do {                                            \
    const char* Ab_ = (const char*)&lds[(sl) * SLOT_US];                     \
    const char* Bb_ = (const char*)&lds[(sl) * SLOT_US + 16384];             \
    int cc_ = ((ksub) * 64 + q4 * 16) ^ lxor;                                \
    _Pragma("unroll") for (int mi = 0; mi < 4; ++mi)                         \
        af[mi] = *(const s16x8*)(Ab_ + (wm * 64 + mi * 16 + r16) * 128 + cc_); \
    _Pragma("unroll") for (int ni = 0; ni < 4; ++ni)                         \
        bf[ni] = *(const s16x8*)(Bb_ + (wn * 64 + ni * 16 + r16) * 128 + cc_); \
} while (0)

#define DO_MFMA() do {                                                       \
    __builtin_amdgcn_s_setprio(1);                                           \
    _Pragma("unroll") for (int mi = 0; mi < 4; ++mi)                         \
    _Pragma("unroll") for (int ni = 0; ni < 4; ++ni)                         \
        acc[mi][ni] = __builtin_amdgcn_mfma_f32_16x16x32_bf16(                \
            af[mi], bf[ni], acc[mi][ni], 0, 0, 0);                           \
    __builtin_amdgcn_s_setprio(0);                                           \
} while (0)

    STAGE_A(0, 0, 0); STAGE_A(0, 0, 1); STAGE_B(0, 0, 0);
    STAGE_A(0, 0, 2); STAGE_A(0, 0, 3); STAGE_B(0, 0, 1);
    STAGE_A(1, 1, 0); STAGE_A(1, 1, 1); STAGE_B(1, 1, 0);
    STAGE_A(1, 1, 2); STAGE_A(1, 1, 3); STAGE_B(1, 1, 1);
    asm volatile("s_waitcnt vmcnt(6)" ::: "memory");
    __builtin_amdgcn_s_barrier();
    asm volatile("" ::: "memory");

    int slot = 0;
    for (int tt = 0; tt < NT; ++tt) {
        int snx = slot + 2; if (snx >= 3) snx -= 3;
        const bool pf = (tt + 2 < NT);

        LOAD_FRAGS(slot, 0);
        if (pf) { STAGE_A(tt + 2, snx, 0); STAGE_A(tt + 2, snx, 1); STAGE_B(tt + 2, snx, 0); }
        asm volatile("" ::: "memory");
        __builtin_amdgcn_s_barrier();
        asm volatile("s_waitcnt lgkmcnt(0)" ::: "memory");
        DO_MFMA();
        asm volatile("" ::: "memory");
        __builtin_amdgcn_s_barrier();
        asm volatile("" ::: "memory");

        LOAD_FRAGS(slot, 1);
        if (pf) { STAGE_A(tt + 2, snx, 2); STAGE_A(tt + 2, snx, 3); STAGE_B(tt + 2, snx, 1); }
        asm volatile("" ::: "memory");
        __builtin_amdgcn_s_barrier();
        asm volatile("s_waitcnt lgkmcnt(0)" ::: "memory");
        DO_MFMA();
        if (pf)               asm volatile("s_waitcnt vmcnt(6)" ::: "memory");
        else if (tt + 1 < NT) asm volatile("s_waitcnt vmcnt(0)" ::: "memory");
        asm volatile("" ::: "memory");
        __builtin_amdgcn_s_barrier();
        asm volatile("" ::: "memory");

        slot = (slot == 2) ? 0 : slot + 1;
    }
#undef STAGE_A
#undef STAGE_B
#undef LOAD_FRAGS
#undef DO_MFMA

#pragma unroll
    for (int mi = 0; mi < 4; ++mi)
#pragma unroll
        for (int ni = 0; ni < 4; ++ni) {
            int n = n0 + wn * 64 + ni * 16 + r16;
#pragma unroll
            for (int r = 0; r < 4; ++r) {
                int m = m0 + wm * 64 + mi * 16 + q4 * 4 + r;
                FO[(size_t)m * Dd + n] = acc[mi][ni][r];
            }
        }
}

// ---------------------------------------------------------------------------
// RoPE in-place on bf16 q,k, vectorized short8 (G13).  16 threads/row,
// 16 rows/block; row lives in one wave.  q scaled by log2(e)/sqrt(128).
// grid: 8192 blocks (0..4095 = q, 4096..8191 = k).
// ---------------------------------------------------------------------------
__global__ __launch_bounds__(256)
void rope_bf16(unsigned short* __restrict__ q, unsigned short* __restrict__ k,
               const float* __restrict__ cosb, const float* __restrict__ sinb)
{
    const float QS = 0.1275175f;           // log2(e)/sqrt(128)
    const int t = threadIdx.x;
    int rblk = blockIdx.x;
    unsigned short* base;
    float sc;
    if (rblk < 4096) { base = q; sc = QS; }
    else             { base = k; sc = 1.0f; rblk -= 4096; }

    const int row = rblk * 16 + (t >> 4);  // [0, B*H*L)
    const int l   = row & (Ll - 1);
    const int d0  = (t & 15) * 8;
    unsigned short* xr = base + (size_t)row * Hd;

    s16x8 v0 = *(const s16x8*)(xr + d0);
    s16x8 vp = *(const s16x8*)(xr + (d0 ^ 64));
    const float* cp = cosb + (size_t)l * Hd + d0;
    const float* sp = sinb + (size_t)l * Hd + d0;
    float4 c0 = *(const float4*)cp,       c1 = *(const float4*)(cp + 4);
    float4 sa = *(const float4*)sp,       sb = *(const float4*)(sp + 4);
    const float cc[8] = {c0.x, c0.y, c0.z, c0.w, c1.x, c1.y, c1.z, c1.w};
    const float ss[8] = {sa.x, sa.y, sa.z, sa.w, sb.x, sb.y, sb.z, sb.w};
    const float sgn = (d0 < 64) ? -1.f : 1.f;

    s16x8 o;
#pragma unroll
    for (int j = 0; j < 8; ++j) {
        float a = bf2f((unsigned short)v0[j]);
        float p = bf2f((unsigned short)vp[j]);
        float res = fmaf(a, cc[j], sgn * p * ss[j]) * sc;
        o[j] = (short)f2bf(res);
    }
    asm volatile("" ::: "memory");         // loads (both halves) before store
    *(s16x8*)(xr + d0) = o;
}

// ---------------------------------------------------------------------------
// Flash attention (r3-proven): 32x32x16 bf16 MFMA, no-max softmax,
// double-buffered async gld_lds staging, XOR-swizzled linear LDS,
// one barrier per 64-key tile, setprio around MFMA clusters.
// LDS = 80 KiB -> 2 blocks/CU.
// ---------------------------------------------------------------------------
__global__ __launch_bounds__(256)
void flash_attn(const unsigned short* __restrict__ q,
                const unsigned short* __restrict__ k,
                const unsigned short* __restrict__ vT,
                unsigned short* __restrict__ ctx)
{
    __shared__ unsigned short Ks[2][64 * 128];   // [key][d] linear
    __shared__ unsigned short Vs[2][128 * 64];   // [d][key] linear
    __shared__ unsigned short Ps[4][32 * 64];    // per-wave [m][key]

    const int t = threadIdx.x;
    const int w = t >> 6, lane = t & 63;
    const int n32 = lane & 31, half = lane >> 5;
    const int bh = blockIdx.x >> 4;              // 16 q-tiles of 128 per (b,h)
    const int l0 = (blockIdx.x & 15) * 128;

    const unsigned short* qb = q  + ((size_t)bh * Ll + l0 + w * 32) * Hd;
    const unsigned short* kb = k  + (size_t)bh * Ll * Hd;
    const unsigned short* vb = vT + (size_t)bh * Hd * Ll;

    const int k_r = lane >> 4, k_u = lane & 15;  // K: 4 rows x 256 B per instr
    const int v_r = lane >> 3, v_u = lane & 7;   // V: 8 rows x 128 B per instr

#define STAGE(J0, bsel) do {                                                  \
    _Pragma("unroll") for (int p = 0; p < 4; ++p) {                           \
        int j_ = w * 4 + p;                                                   \
        int row_ = j_ * 4 + k_r;                                              \
        gld16(kb + (size_t)((J0) + row_) * Hd + ((k_u ^ (row_ & 7)) * 8),     \
              &Ks[bsel][j_ * 512]);                                           \
    }                                                                         \
    _Pragma("unroll") for (int p = 0; p < 4; ++p) {                           \
        int j_ = w * 4 + p;                                                   \
        int row_ = j_ * 8 + v_r;                                              \
        gld16(vb + (size_t)row_ * Ll + (J0) + ((v_u ^ (row_ & 7)) * 8),       \
              &Vs[bsel][j_ * 512]);                                           \
    }                                                                         \
} while (0)

    s16x8 qf[8];
#pragma unroll
    for (int ks = 0; ks < 8; ++ks)
        qf[ks] = *(const s16x8*)(qb + (size_t)n32 * Hd + ks * 16 + half * 8);

    f32x16 o[4];
    float lacc[16];
#pragma unroll
    for (int nt = 0; nt < 4; ++nt)
#pragma unroll
        for (int r = 0; r < 16; ++r) o[nt][r] = 0.f;
#pragma unroll
    for (int r = 0; r < 16; ++r) lacc[r] = 0.f;

    unsigned short* Pw = Ps[w];
    const int psw = (n32 & 7) << 3;              // read-side swizzle (row n32)

    STAGE(0, 0);
    __syncthreads();

    int buf = 0;
    for (int j0 = 0; j0 < Ll; j0 += 64) {
        if (j0 + 64 < Ll) STAGE(j0 + 64, buf ^ 1);   // in flight across compute

        f32x16 s0, s1;
#pragma unroll
        for (int r = 0; r < 16; ++r) { s0[r] = 0.f; s1[r] = 0.f; }
        __builtin_amdgcn_s_setprio(1);
#pragma unroll
        for (int ks = 0; ks < 8; ++ks) {
            int kc = (ks * 16 + half * 8) ^ psw;
            s16x8 b0 = *(const s16x8*)&Ks[buf][n32 * 128 + kc];
            s16x8 b1 = *(const s16x8*)&Ks[buf][(32 + n32) * 128 + kc];
            s0 = __builtin_amdgcn_mfma_f32_32x32x16_bf16(qf[ks], b0, s0, 0, 0, 0);
            s1 = __builtin_amdgcn_mfma_f32_32x32x16_bf16(qf[ks], b1, s1, 0, 0, 0);
        }
        __builtin_amdgcn_s_setprio(0);

#pragma unroll
        for (int r = 0; r < 16; ++r) {
            int mrow = (r & 3) + 8 * (r >> 2) + 4 * half;
            int sw = (mrow & 7) << 3;
            float p0 = fast_exp2(s0[r]);
            float p1 = fast_exp2(s1[r]);
            lacc[r] += p0 + p1;
            union { float f; unsigned u; } u0, u1;
            u0.f = p0; u1.f = p1;
            Pw[mrow * 64 + (n32 ^ sw)]        = (unsigned short)((u0.u + 0x8000u) >> 16);
            Pw[mrow * 64 + ((32 + n32) ^ sw)] = (unsigned short)((u1.u + 0x8000u) >> 16);
        }

        __builtin_amdgcn_s_setprio(1);
#pragma unroll
        for (int kst = 0; kst < 4; ++kst) {
            int cc = (kst * 16 + half * 8) ^ psw;
            s16x8 pf2 = *(const s16x8*)&Pw[n32 * 64 + cc];
#pragma unroll
            for (int nt = 0; nt < 4; ++nt) {
                s16x8 vf = *(const s16x8*)&Vs[buf][(nt * 32 + n32) * 64 + cc];
                o[nt] = __builtin_amdgcn_mfma_f32_32x32x16_bf16(pf2, vf, o[nt], 0, 0, 0);
            }
        }
        __builtin_amdgcn_s_setprio(0);

        __syncthreads();     // drains vmcnt(0): next tile staged; buffer swap
        buf ^= 1;
    }
#undef STAGE

    float linv[16];
#pragma unroll
    for (int r = 0; r < 16; ++r) {
        float s = lacc[r];
        s += __shfl_xor(s, 1, 64);
        s += __shfl_xor(s, 2, 64);
        s += __shfl_xor(s, 4, 64);
        s += __shfl_xor(s, 8, 64);
        s += __shfl_xor(s, 16, 64);
        linv[r] = 1.0f / s;
    }

    const int b = bh >> 4, h = bh & 15;
#pragma unroll
    for (int nt = 0; nt < 4; ++nt)
#pragma unroll
        for (int r = 0; r < 16; ++r) {
            int mrow = (r & 3) + 8 * (r >> 2) + 4 * half;
            int lq = l0 + w * 32 + mrow;
            ctx[((size_t)(b * Ll + lq)) * Dd + h * Hd + nt * 32 + n32] =
                f2bf(o[nt][r] * linv[r]);
        }
}

// ---------------------------------------------------------------------------
// Workspace (96 MB): [Xb 16M][Wq 8M][Wk 8M][Wv 8M][Wo 8M][q 16M][k 16M][vT 16M]
// Wq/Wk/Wv contiguous -> fused QKV GEMM reads them as one [6144][2048] W.
// ctx reuses the Xb slot (X dead after QKV GEMM).
// ---------------------------------------------------------------------------
extern "C" void kernel_launch(void* const* d_in, const int* in_sizes, int n_in,
                              void* d_out, int out_size, void* d_ws, size_t ws_size,
                              hipStream_t stream)
{
    const float* hs   = (const float*)d_in[0];
    const float* cosb = (const float*)d_in[1];
    const float* sinb = (const float*)d_in[2];
    const float* wq   = (const float*)d_in[3];
    const float* wk   = (const float*)d_in[4];
    const float* wv   = (const float*)d_in[5];
    const float* wo   = (const float*)d_in[6];
    float* out = (float*)d_out;

    char* ws = (char*)d_ws;
    unsigned short* Xb  = (unsigned short*)(ws);
    unsigned short* Wqb = (unsigned short*)(ws + (16ull << 20));
    unsigned short* Wkb = (unsigned short*)(ws + (24ull << 20));
    unsigned short* Wvb = (unsigned short*)(ws + (32ull << 20));
    unsigned short* Wob = (unsigned short*)(ws + (40ull << 20));
    unsigned short* qb  = (unsigned short*)(ws + (48ull << 20));
    unsigned short* kb  = (unsigned short*)(ws + (64ull << 20));
    unsigned short* vTb = (unsigned short*)(ws + (80ull << 20));
    unsigned short* ctx = Xb;

    const int nX = M * Dd;          // 8388608
    const int nW = Dd * Dd;         // 4194304

    f2bf_kernel<<<dim3(nX / 4 / 256), dim3(256), 0, stream>>>(hs, Xb, nX);
    f2bf_kernel<<<dim3(nW / 4 / 256), dim3(256), 0, stream>>>(wq, Wqb, nW);
    f2bf_kernel<<<dim3(nW / 4 / 256), dim3(256), 0, stream>>>(wk, Wkb, nW);
    f2bf_kernel<<<dim3(nW / 4 / 256), dim3(256), 0, stream>>>(wv, Wvb, nW);
    f2bf_kernel<<<dim3(nW / 4 / 256), dim3(256), 0, stream>>>(wo, Wob, nW);

    // Fused QKV projection: A [4096x2048] x W [6144x2048]^T
    // grid 32x16 = 512 blocks = exactly 2 full rounds of 256 CUs
    mfma_gemm_qkv<<<dim3(6144 / 192, M / 256), dim3(512), 0, stream>>>(
        Xb, Wqb, qb, kb, vTb);

    // RoPE: 16 rows/block, vectorized; blocks 0..4095 = q, 4096..8191 = k
    rope_bf16<<<dim3(2 * (Bb * Hh * Ll) / 16), dim3(256), 0, stream>>>(
        qb, kb, cosb, sinb);

    // Flash attention: 128 q-rows/block, 512 blocks (exactly 2/CU)
    flash_attn<<<dim3(Bb * Hh * (Ll / 128)), dim3(256), 0, stream>>>(qb, kb, vTb, ctx);

    // Output projection -> fp32 d_out (256 blocks = 1 full round)
    mfma_gemm_out<<<dim3(Dd / 128, M / 256), dim3(512), 0, stream>>>(
        ctx, Wob, out);
}